// Round 1
// baseline (744.400 us; speedup 1.0000x reference)
//
#include <hip/hip_runtime.h>
#include <stdint.h>

#define D_DIM 256
#define N_EMB 8192
#define M_TOT 16384
#define TM 64
#define TN 64
#define NCHUNK (N_EMB / TN)
#define QK_SCALE 0.0625f
#define DELTA 4e-3f
#define LN_EPS 1e-5f

typedef _Float16 f16;
typedef f16 f16x8 __attribute__((ext_vector_type(8)));
typedef f16 f16x4 __attribute__((ext_vector_type(4)));
typedef float f32x4 __attribute__((ext_vector_type(4)));

// ws layout:
// [0, 4MB)        embd_h   [8192][256] f16   (n-major, for QK B-frags)
// [4MB, 8MB)      embd_th  [256][8192] f16   (d-major, for PV B-frags)
// [8MB, 8MB+4)    count    (uint)
// [8MB+64, +64KB) list     int[16384]
#define WS_EMBD_H 0u
#define WS_EMBD_TH (4u << 20)
#define WS_COUNT (8u << 20)
#define WS_LIST ((8u << 20) + 64u)

// ---------------- prep: fp32 embd -> f16 in both layouts ----------------
__global__ __launch_bounds__(256) void prep_kernel(const float* __restrict__ embd,
                                                   f16* __restrict__ embd_h,
                                                   f16* __restrict__ embd_th,
                                                   unsigned* __restrict__ count) {
  if (blockIdx.x == 0 && threadIdx.x == 0) *count = 0u;
  __shared__ f16 tile[64][72];
  const int t = threadIdx.x;
  const int nb = (blockIdx.x >> 2) * 64;
  const int db = (blockIdx.x & 3) * 64;
  const int nl = t >> 2;
  const int dl = (t & 3) * 16;
  const float4* src = (const float4*)(embd + (size_t)(nb + nl) * 256 + db + dl);
  f16 vals[16];
#pragma unroll
  for (int q = 0; q < 4; ++q) {
    float4 v = src[q];
    vals[q * 4 + 0] = (f16)v.x;
    vals[q * 4 + 1] = (f16)v.y;
    vals[q * 4 + 2] = (f16)v.z;
    vals[q * 4 + 3] = (f16)v.w;
  }
  f16* dst = embd_h + (size_t)(nb + nl) * 256 + db + dl;
#pragma unroll
  for (int q = 0; q < 2; ++q) {
    f16x8 pack;
#pragma unroll
    for (int j = 0; j < 8; ++j) pack[j] = vals[q * 8 + j];
    *(f16x8*)(dst + q * 8) = pack;
  }
#pragma unroll
  for (int j = 0; j < 16; ++j) tile[nl][dl + j] = vals[j];
  __syncthreads();
  const int dl2 = t >> 2;
  const int nbase = (t & 3) * 16;
  f16* dstT = embd_th + (size_t)(db + dl2) * 8192 + nb + nbase;
#pragma unroll
  for (int q = 0; q < 2; ++q) {
    f16x8 pack;
#pragma unroll
    for (int j = 0; j < 8; ++j) pack[j] = tile[nbase + q * 8 + j][dl2];
    *(f16x8*)(dstT + q * 8) = pack;
  }
}

// ---------------- fused: LN + flash softmax-quantize ----------------
// LDS map: [0,32768) x-tile (phase1) then embd_nd tile [64n][256d] swizzled
//          [32768,49152) embd_dn half-tile [128d][64n] swizzled
//          [49152,57344) P buffers, 2KB/wave
__global__ __launch_bounds__(256) void fused_kernel(
    const float* __restrict__ input, const float* __restrict__ ln_w,
    const float* __restrict__ ln_b, const f16* __restrict__ embd_h,
    const f16* __restrict__ embd_th, float* __restrict__ out_q,
    float* __restrict__ out_idx, unsigned* __restrict__ count,
    int* __restrict__ list) {
  __shared__ __align__(16) char lds[57344];
  const int tid = threadIdx.x;
  const int lane = tid & 63;
  const int w = tid >> 6;
  const int cl = lane & 15;
  const int g = lane >> 4;
  const int R0 = blockIdx.x * TM;

  // ---- Phase 1: LayerNorm 64 rows -> x tile (f16, XOR-swizzled) ----
  {
    const int r = tid >> 2;
    const int seg = tid & 3;
    const float* rowp = input + (size_t)(R0 + r) * 256 + seg * 64;
    float s = 0.f, ss = 0.f;
#pragma unroll
    for (int q = 0; q < 16; ++q) {
      float4 x4 = ((const float4*)rowp)[q];
      s += x4.x + x4.y + x4.z + x4.w;
      ss += x4.x * x4.x + x4.y * x4.y + x4.z * x4.z + x4.w * x4.w;
    }
    s += __shfl_xor(s, 1);
    s += __shfl_xor(s, 2);
    ss += __shfl_xor(ss, 1);
    ss += __shfl_xor(ss, 2);
    const float mean = s * (1.f / 256.f);
    const float var = ss * (1.f / 256.f) - mean * mean;
    const float rstd = 1.0f / sqrtf(var + LN_EPS);
#pragma unroll
    for (int q = 0; q < 16; ++q) {
      float4 x4 = ((const float4*)rowp)[q];
      float4 w4 = ((const float4*)(ln_w + seg * 64))[q];
      float4 b4 = ((const float4*)(ln_b + seg * 64))[q];
      f16x4 h;
      h[0] = (f16)((x4.x - mean) * rstd * w4.x + b4.x);
      h[1] = (f16)((x4.y - mean) * rstd * w4.y + b4.y);
      h[2] = (f16)((x4.z - mean) * rstd * w4.z + b4.z);
      h[3] = (f16)((x4.w - mean) * rstd * w4.w + b4.w);
      const int d = seg * 64 + q * 4;
      const int byte = (r * 512 + d * 2) ^ ((r & 7) << 4);
      *(f16x4*)(lds + byte) = h;
    }
  }
  __syncthreads();

  // ---- Q fragments to registers ----
  f16x8 Q[8];
  {
    const int r = w * 16 + cl;
#pragma unroll
    for (int kc = 0; kc < 8; ++kc) {
      const int unit = kc * 4 + g;  // d = kc*32 + g*8, 16B unit index
      Q[kc] = *(const f16x8*)(lds + r * 512 + ((unit ^ (r & 7)) << 4));
    }
  }

  f32x4 acc[16] = {};
  float m_run[4], l_run[4], m2_run[4];
  int i1_run[4];
#pragma unroll
  for (int i = 0; i < 4; ++i) {
    m_run[i] = -__builtin_inff();
    m2_run[i] = -__builtin_inff();
    l_run[i] = 0.f;
    i1_run[i] = 0;
  }

  for (int c = 0; c < NCHUNK; ++c) {
    __syncthreads();  // previous chunk reads (and Q-frag loads) done
    // stage embd_nd [64][256] f16 swizzled
    {
      const f16x8* srcN = (const f16x8*)(embd_h + (size_t)c * (TN * 256));
#pragma unroll
      for (int i = 0; i < 8; ++i) {
        const int u = i * 256 + tid;
        const int n = u >> 5, un = u & 31;
        f16x8 val = srcN[u];
        *(f16x8*)(lds + n * 512 + ((un ^ (n & 7)) << 4)) = val;
      }
      // stage embd_dn rows d=0..127
      const char* srcT = (const char*)embd_th + (size_t)c * 128;
#pragma unroll
      for (int i = 0; i < 4; ++i) {
        const int u = i * 256 + tid;  // 0..1023
        const int d = u >> 3, j = u & 7;
        f16x8 val = *(const f16x8*)(srcT + (size_t)d * 16384 + j * 16);
        *(f16x8*)(lds + 32768 + d * 128 + ((j ^ (d & 7)) << 4)) = val;
      }
    }
    __syncthreads();

    // ---- QK^T: S[fn] = X(16x256) * E^T, 32 MFMA ----
    f32x4 S[4] = {};
#pragma unroll
    for (int kc = 0; kc < 8; ++kc) {
#pragma unroll
      for (int fn = 0; fn < 4; ++fn) {
        const int n = fn * 16 + cl;
        f16x8 b =
            *(const f16x8*)(lds + n * 512 + (((kc * 4 + g) ^ (n & 7)) << 4));
        S[fn] = __builtin_amdgcn_mfma_f32_16x16x32_f16(Q[kc], b, S[fn], 0, 0, 0);
      }
    }

    // ---- online softmax + top-2 tracking ----
    const int nb = c * TN;
    float sv[4][4];  // [row i][fn]
#pragma unroll
    for (int fn = 0; fn < 4; ++fn)
#pragma unroll
      for (int i = 0; i < 4; ++i) sv[i][fn] = S[fn][i] * QK_SCALE;

    float alpha[4];
    int grow = 0;
#pragma unroll
    for (int i = 0; i < 4; ++i) {
      const float a0 = sv[i][0], a1 = sv[i][1], a2 = sv[i][2], a3 = sv[i][3];
      const int j0 = nb + cl, j1 = nb + 16 + cl, j2 = nb + 32 + cl,
                j3 = nb + 48 + cl;
      float hi1, lo1, hi2, lo2;
      int ii1, ii2;
      if (a1 > a0) { hi1 = a1; ii1 = j1; lo1 = a0; }
      else { hi1 = a0; ii1 = j0; lo1 = a1; }
      if (a3 > a2) { hi2 = a3; ii2 = j3; lo2 = a2; }
      else { hi2 = a2; ii2 = j2; lo2 = a3; }
      float t1, t2;
      int ti;
      if (hi2 > hi1) { t1 = hi2; ti = ii2; t2 = fmaxf(lo2, hi1); }
      else { t1 = hi1; ti = ii1; t2 = fmaxf(lo1, hi2); }
#pragma unroll
      for (int mk = 1; mk <= 8; mk <<= 1) {
        const float ov1 = __shfl_xor(t1, mk);
        const int oi = __shfl_xor(ti, mk);
        const float ov2 = __shfl_xor(t2, mk);
        if (ov1 > t1) { t2 = fmaxf(t1, ov2); t1 = ov1; ti = oi; }
        else { t2 = fmaxf(t2, ov1); }
      }
      const float mold = m_run[i];
      if (t1 > mold) { m2_run[i] = fmaxf(mold, t2); i1_run[i] = ti; grow = 1; }
      else { m2_run[i] = fmaxf(m2_run[i], t1); }
      const float mnew = fmaxf(mold, t1);
      alpha[i] = __expf(mold - mnew);
      m_run[i] = mnew;
    }
    // p = exp(s - m), row sums, l update
#pragma unroll
    for (int i = 0; i < 4; ++i) {
      float rsum = 0.f;
#pragma unroll
      for (int fn = 0; fn < 4; ++fn) {
        const float p = __expf(sv[i][fn] - m_run[i]);
        sv[i][fn] = p;
        rsum += p;
      }
      rsum += __shfl_xor(rsum, 1);
      rsum += __shfl_xor(rsum, 2);
      rsum += __shfl_xor(rsum, 4);
      rsum += __shfl_xor(rsum, 8);
      l_run[i] = l_run[i] * alpha[i] + rsum;
    }
    // rescale acc (skipped when no row max grew anywhere in wave)
    if (__any(grow)) {
#pragma unroll
      for (int f = 0; f < 16; ++f) {
        acc[f][0] *= alpha[0];
        acc[f][1] *= alpha[1];
        acc[f][2] *= alpha[2];
        acc[f][3] *= alpha[3];
      }
    }
    // ---- P -> f16 -> per-wave LDS buffer (C-layout write) ----
    char* Pb = lds + 49152 + w * 2048;
#pragma unroll
    for (int i = 0; i < 4; ++i) {
      const int r = g * 4 + i;
#pragma unroll
      for (int fn = 0; fn < 4; ++fn) {
        const int off = (r * 128 + (fn * 16 + cl) * 2) ^ ((r & 7) << 4);
        *(f16*)(Pb + off) = (f16)sv[i][fn];
      }
    }
    // ---- PV: acc += P(16x64) * V(64x256) ----
    f16x8 pa[2];
#pragma unroll
    for (int k2 = 0; k2 < 2; ++k2)
      pa[k2] =
          *(const f16x8*)(Pb + cl * 128 + (((k2 * 4 + g) ^ (cl & 7)) << 4));
#pragma unroll
    for (int f = 0; f < 8; ++f) {
      const int d = f * 16 + cl;
#pragma unroll
      for (int k2 = 0; k2 < 2; ++k2) {
        f16x8 vb = *(const f16x8*)(lds + 32768 + d * 128 +
                                   (((k2 * 4 + g) ^ (d & 7)) << 4));
        acc[f] = __builtin_amdgcn_mfma_f32_16x16x32_f16(pa[k2], vb, acc[f], 0, 0, 0);
      }
    }
    __syncthreads();
    // restage embd_dn rows d=128..255
    {
      const char* srcT = (const char*)embd_th + (size_t)c * 128;
#pragma unroll
      for (int i = 0; i < 4; ++i) {
        const int u = i * 256 + tid + 1024;
        const int d = u >> 3, j = u & 7;
        f16x8 val = *(const f16x8*)(srcT + (size_t)d * 16384 + j * 16);
        *(f16x8*)(lds + 32768 + (d - 128) * 128 + ((j ^ (d & 7)) << 4)) = val;
      }
    }
    __syncthreads();
#pragma unroll
    for (int f = 8; f < 16; ++f) {
      const int d = f * 16 + cl;
      const int dl = d - 128;
#pragma unroll
      for (int k2 = 0; k2 < 2; ++k2) {
        f16x8 vb = *(const f16x8*)(lds + 32768 + dl * 128 +
                                   (((k2 * 4 + g) ^ (d & 7)) << 4));
        acc[f] = __builtin_amdgcn_mfma_f32_16x16x32_f16(pa[k2], vb, acc[f], 0, 0, 0);
      }
    }
  }

  // ---- epilogue ----
  float invl[4];
#pragma unroll
  for (int i = 0; i < 4; ++i) invl[i] = 1.0f / l_run[i];
#pragma unroll
  for (int f = 0; f < 16; ++f) {
#pragma unroll
    for (int i = 0; i < 4; ++i) {
      const int r = R0 + w * 16 + g * 4 + i;
      out_q[(size_t)r * 256 + f * 16 + cl] = acc[f][i] * invl[i];
    }
  }
  if (cl == 0) {
#pragma unroll
    for (int i = 0; i < 4; ++i) {
      const int r = R0 + w * 16 + g * 4 + i;
      out_idx[r] = (float)i1_run[i];
      if (m_run[i] - m2_run[i] <= DELTA) {
        const unsigned pos = atomicAdd(count, 1u);
        list[pos] = r;
      }
    }
  }
}

// ---------------- refine: exact fp32 argmax for flagged rows ----------------
__global__ __launch_bounds__(256) void refine_kernel(
    const float* __restrict__ input, const float* __restrict__ ln_w,
    const float* __restrict__ ln_b, const float* __restrict__ embd,
    float* __restrict__ out_idx, const unsigned* __restrict__ count,
    const int* __restrict__ list) {
  __shared__ float xr[2][256];
  __shared__ float redv[256];
  __shared__ int redi[256];
  __shared__ float stat[8];
  const int tid = threadIdx.x;
  const unsigned cnt = *count;
  for (unsigned t = blockIdx.x; t * 2u < cnt; t += gridDim.x) {
    const unsigned rem = cnt - t * 2u;
    const int nrows = rem >= 2u ? 2 : 1;
    for (int rr = 0; rr < 2; ++rr) {
      const int row = list[t * 2u + (unsigned)(rr < nrows ? rr : 0)];
      const float v = input[(size_t)row * 256 + tid];
      float s = v, ss = v * v;
#pragma unroll
      for (int mk = 1; mk <= 32; mk <<= 1) {
        s += __shfl_xor(s, mk);
        ss += __shfl_xor(ss, mk);
      }
      if ((tid & 63) == 0) {
        stat[tid >> 6] = s;
        stat[4 + (tid >> 6)] = ss;
      }
      __syncthreads();
      const float S_ = stat[0] + stat[1] + stat[2] + stat[3];
      const float SS = stat[4] + stat[5] + stat[6] + stat[7];
      const float mean = S_ * (1.f / 256.f);
      const float var = SS * (1.f / 256.f) - mean * mean;
      const float rstd = 1.0f / sqrtf(var + LN_EPS);
      xr[rr][tid] = (v - mean) * rstd * ln_w[tid] + ln_b[tid];
      __syncthreads();
    }
    float b0 = -__builtin_inff(), b1 = -__builtin_inff();
    int i0 = 0, i1_ = 0;
    for (int n = tid; n < 8192; n += 256) {
      const float4* e4 = (const float4*)(embd + (size_t)n * 256);
      float d0 = 0.f, d1 = 0.f;
#pragma unroll 8
      for (int q = 0; q < 64; ++q) {
        const float4 e = e4[q];
        const float4 x0 = *(const float4*)&xr[0][q * 4];
        const float4 x1 = *(const float4*)&xr[1][q * 4];
        d0 += x0.x * e.x + x0.y * e.y + x0.z * e.z + x0.w * e.w;
        d1 += x1.x * e.x + x1.y * e.y + x1.z * e.z + x1.w * e.w;
      }
      if (d0 > b0) { b0 = d0; i0 = n; }
      if (d1 > b1) { b1 = d1; i1_ = n; }
    }
    for (int rr = 0; rr < nrows; ++rr) {
      __syncthreads();
      redv[tid] = rr ? b1 : b0;
      redi[tid] = rr ? i1_ : i0;
      __syncthreads();
      for (int off = 128; off > 0; off >>= 1) {
        if (tid < off) {
          const float ov = redv[tid + off];
          const int oi = redi[tid + off];
          if (ov > redv[tid] || (ov == redv[tid] && oi < redi[tid])) {
            redv[tid] = ov;
            redi[tid] = oi;
          }
        }
        __syncthreads();
      }
      if (tid == 0) out_idx[list[t * 2u + rr]] = (float)redi[0];
    }
  }
}

extern "C" void kernel_launch(void* const* d_in, const int* in_sizes, int n_in,
                              void* d_out, int out_size, void* d_ws,
                              size_t ws_size, hipStream_t stream) {
  (void)in_sizes;
  (void)n_in;
  (void)out_size;
  (void)ws_size;
  const float* input = (const float*)d_in[0];
  const float* ln_w = (const float*)d_in[1];
  const float* ln_b = (const float*)d_in[2];
  const float* embd = (const float*)d_in[3];
  float* out_q = (float*)d_out;
  float* out_idx = out_q + (size_t)M_TOT * D_DIM;
  char* ws = (char*)d_ws;
  f16* embd_h = (f16*)(ws + WS_EMBD_H);
  f16* embd_th = (f16*)(ws + WS_EMBD_TH);
  unsigned* count = (unsigned*)(ws + WS_COUNT);
  int* list = (int*)(ws + WS_LIST);

  prep_kernel<<<512, 256, 0, stream>>>(embd, embd_h, embd_th, count);
  fused_kernel<<<256, 256, 0, stream>>>(input, ln_w, ln_b, embd_h, embd_th,
                                        out_q, out_idx, count, list);
  refine_kernel<<<128, 256, 0, stream>>>(input, ln_w, ln_b, embd, out_idx,
                                         count, list);
}